// Round 1
// baseline (316.668 us; speedup 1.0000x reference)
//
#include <hip/hip_runtime.h>
#include <hip/hip_bf16.h>

typedef unsigned short u16;
typedef __attribute__((ext_vector_type(8))) short short8v;   // 8 bf16 (4 VGPR)
typedef __attribute__((ext_vector_type(4))) float float4v;   // 4 f32 acc

#define BM 128
#define BN 128
#define BK 32

__device__ inline u16 f2b(float f) {
  __hip_bfloat16 h = __float2bfloat16(f);
  union { __hip_bfloat16 h; u16 s; } u;
  u.h = h;
  return u.s;
}

__device__ inline void gload_lds16(const u16* g, u16* l) {
  __builtin_amdgcn_global_load_lds(
      (const __attribute__((address_space(1))) void*)g,
      (__attribute__((address_space(3))) void*)l, 16, 0, 0);
}

// ---------------------------------------------------------------------------
// fp32 -> bf16 conversion (vectorized, grid-stride)
// ---------------------------------------------------------------------------
__global__ __launch_bounds__(256) void cvt_f32_bf16(const float* __restrict__ in,
                                                    u16* __restrict__ out, int n4) {
  for (int i = blockIdx.x * blockDim.x + threadIdx.x; i < n4;
       i += gridDim.x * blockDim.x) {
    float4 v = ((const float4*)in)[i];
    ushort4 o;
    o.x = f2b(v.x); o.y = f2b(v.y); o.z = f2b(v.z); o.w = f2b(v.w);
    ((ushort4*)out)[i] = o;
  }
}

// ---------------------------------------------------------------------------
// gemm_bt: C[m][n] = sum_k A[m][k] * B[n][k]   (both row-major, K contiguous)
// 128x128 tile, BK=32, 4 waves (2x2 of 64x64), mfma_f32_16x16x32_bf16.
// causal_mode: 0 = none; 1 = skip tile if n0 > m0+BM (scores);
//              2 = cap K at m0+BM+1 (PV; needs A zero-padded past cap).
// Cf != nullptr -> write fp32, else write bf16 to Cb.
// ---------------------------------------------------------------------------
__global__ __launch_bounds__(256)
void gemm_bt_kernel(const u16* __restrict__ A, int lda,
                    const u16* __restrict__ B, int ldb,
                    u16* __restrict__ Cb, float* __restrict__ Cf, int ldc,
                    int K, int causal_mode) {
  __shared__ __align__(16) u16 lds[2][2][BM * BK];

  const int m0 = blockIdx.x * BM;
  const int n0 = blockIdx.y * BN;
  if (causal_mode == 1 && n0 > m0 + BM) return;  // fully masked tile
  int Keff = K;
  if (causal_mode == 2) {
    int cap = m0 + BM + 1;
    if (cap < Keff) Keff = cap;
  }
  const int nk = (Keff + BK - 1) / BK;

  const int tid  = threadIdx.x;
  const int lane = tid & 63;
  const int wid  = tid >> 6;
  const int wr   = wid >> 1;   // 2x2 wave grid, each wave owns 64x64
  const int wc   = wid & 1;

  // staging: thread t loads 16B chunks t and t+256 of each 8KB tile.
  // chunk c -> row c>>2, k-offset (c&3)*8 ; LDS byte offset = c*16 (linear).
  const u16* ga = A + (long)(m0 + (tid >> 2)) * lda + (tid & 3) * 8;
  const u16* gb = B + (long)(n0 + (tid >> 2)) * ldb + (tid & 3) * 8;

  float4v acc[4][4];
#pragma unroll
  for (int i = 0; i < 4; ++i)
#pragma unroll
    for (int j = 0; j < 4; ++j)
      acc[i][j] = (float4v){0.f, 0.f, 0.f, 0.f};

  auto stage = [&](int b, int kt) {
    const int k0 = kt * BK;
    gload_lds16(ga + k0,            &lds[b][0][tid * 8]);
    gload_lds16(ga + 64 * lda + k0, &lds[b][0][(tid + 256) * 8]);
    gload_lds16(gb + k0,            &lds[b][1][tid * 8]);
    gload_lds16(gb + 64 * ldb + k0, &lds[b][1][(tid + 256) * 8]);
  };

  stage(0, 0);
  int buf = 0;

  const int arow = wr * 64 + (lane & 15);
  const int brow = wc * 64 + (lane & 15);
  const int koff = (lane >> 4) * 8;

  for (int kt = 0; kt < nk; ++kt) {
    __syncthreads();  // staging of buf complete (compiler drains vmcnt)
    if (kt + 1 < nk) stage(buf ^ 1, kt + 1);
    const u16* la = lds[buf][0];
    const u16* lb = lds[buf][1];
    short8v af[4], bfr[4];
#pragma unroll
    for (int mi = 0; mi < 4; ++mi)
      af[mi] = *(const short8v*)&la[(arow + mi * 16) * BK + koff];
#pragma unroll
    for (int ni = 0; ni < 4; ++ni)
      bfr[ni] = *(const short8v*)&lb[(brow + ni * 16) * BK + koff];
#pragma unroll
    for (int mi = 0; mi < 4; ++mi)
#pragma unroll
      for (int ni = 0; ni < 4; ++ni)
        acc[mi][ni] = __builtin_amdgcn_mfma_f32_16x16x32_bf16(
            af[mi], bfr[ni], acc[mi][ni], 0, 0, 0);
    buf ^= 1;
  }

  // C/D layout (m89-verified): col = lane&15, row = (lane>>4)*4 + reg
  const int r0base = m0 + wr * 64 + ((lane >> 4) << 2);
  const int cbase  = n0 + wc * 64 + (lane & 15);
#pragma unroll
  for (int mi = 0; mi < 4; ++mi) {
#pragma unroll
    for (int ni = 0; ni < 4; ++ni) {
      const int r0 = r0base + mi * 16;
      const int c  = cbase + ni * 16;
#pragma unroll
      for (int r = 0; r < 4; ++r) {
        if (Cf) Cf[(long)(r0 + r) * ldc + c] = acc[mi][ni][r];
        else    Cb[(long)(r0 + r) * ldc + c] = f2b(acc[mi][ni][r]);
      }
    }
  }
}

// ---------------------------------------------------------------------------
// masked scaled softmax over one row; writes P (bf16) zero-padded to T.
// mask: row i sees j <= i+1.  scale = 1/sqrt(1024) = 1/32.
// ---------------------------------------------------------------------------
__global__ __launch_bounds__(256)
void softmax_kernel(const float* __restrict__ S, u16* __restrict__ P, int T) {
  const int i    = blockIdx.x;
  const int nvis = min(i + 2, T);
  const float scale = 0.03125f;

  __shared__ float row[2048];
  __shared__ float red[4];

  float m = -INFINITY;
  for (int j = threadIdx.x; j < nvis; j += 256) {
    float v = S[(long)i * T + j] * scale;
    row[j] = v;
    m = fmaxf(m, v);
  }
#pragma unroll
  for (int o = 32; o; o >>= 1) m = fmaxf(m, __shfl_xor(m, o));
  const int wid = threadIdx.x >> 6;
  if ((threadIdx.x & 63) == 0) red[wid] = m;
  __syncthreads();
  m = fmaxf(fmaxf(red[0], red[1]), fmaxf(red[2], red[3]));
  __syncthreads();

  float s = 0.f;
  for (int j = threadIdx.x; j < nvis; j += 256) s += __expf(row[j] - m);
#pragma unroll
  for (int o = 32; o; o >>= 1) s += __shfl_xor(s, o);
  if ((threadIdx.x & 63) == 0) red[wid] = s;
  __syncthreads();
  s = red[0] + red[1] + red[2] + red[3];
  const float inv = 1.0f / s;

  for (int j = threadIdx.x; j < T; j += 256) {
    float p = (j < nvis) ? __expf(row[j] - m) * inv : 0.0f;
    P[(long)i * T + j] = f2b(p);
  }
}

// ---------------------------------------------------------------------------
extern "C" void kernel_launch(void* const* d_in, const int* in_sizes, int n_in,
                              void* d_out, int out_size, void* d_ws, size_t ws_size,
                              hipStream_t stream) {
  const float* x  = (const float*)d_in[0];
  const float* Wq = (const float*)d_in[1];
  const float* Wk = (const float*)d_in[2];
  const float* Wv = (const float*)d_in[3];
  float* out = (float*)d_out;

  const int B = 4, T = 2048, D = 1024;
  const int M = B * T;  // 8192

  char* ws = (char*)d_ws;
  u16* xb   = (u16*)(ws);                                  // 16 MiB  (8192x1024)
  u16* wqb  = (u16*)(ws + 16777216);                       // 2 MiB
  u16* wkb  = wqb + 1048576;
  u16* wvb  = wkb + 1048576;
  u16* qb   = (u16*)(ws + 16777216 + 6291456);             // 16 MiB
  u16* kb   = qb + 8388608;                                // 16 MiB
  u16* vtb  = kb + 8388608;                                // 16 MiB  (1024x8192, d-major)
  float* S  = (float*)(ws + 16777216 + 6291456 + 50331648);// 16 MiB  (2048x2048 f32)
  u16* P    = (u16*)((char*)S + 16777216);                 // 8 MiB   (2048x2048 bf16)
  // total: 98,566,144 bytes

  // fp32 -> bf16
  cvt_f32_bf16<<<2048, 256, 0, stream>>>(x,  xb,  (M * D) / 4);
  cvt_f32_bf16<<<512,  256, 0, stream>>>(Wq, wqb, (D * D) / 4);
  cvt_f32_bf16<<<512,  256, 0, stream>>>(Wk, wkb, (D * D) / 4);
  cvt_f32_bf16<<<512,  256, 0, stream>>>(Wv, wvb, (D * D) / 4);

  // projections: q = x Wq^T, k = x Wk^T  (8192x1024),  vt = Wv x^T (1024x8192)
  gemm_bt_kernel<<<dim3(M / BM, D / BN), 256, 0, stream>>>(
      xb, D, wqb, D, qb, nullptr, D, D, 0);
  gemm_bt_kernel<<<dim3(M / BM, D / BN), 256, 0, stream>>>(
      xb, D, wkb, D, kb, nullptr, D, D, 0);
  gemm_bt_kernel<<<dim3(D / BM, M / BN), 256, 0, stream>>>(
      wvb, D, xb, D, vtb, nullptr, M, D, 0);

  for (int b = 0; b < B; ++b) {
    const u16* qbb = qb + (long)b * T * D;
    const u16* kbb = kb + (long)b * T * D;
    // S = q k^T  (2048x2048, fp32), skip fully-masked tiles
    gemm_bt_kernel<<<dim3(T / BM, T / BN), 256, 0, stream>>>(
        qbb, D, kbb, D, nullptr, S, T, D, 1);
    // masked scaled softmax -> P (bf16, zero-padded)
    softmax_kernel<<<T, 256, 0, stream>>>(S, P, T);
    // O = P V = P (vt)^T ; K capped at m0+129 per tile-row
    gemm_bt_kernel<<<dim3(T / BM, D / BN), 256, 0, stream>>>(
        P, T, vtb + (long)b * T, M, nullptr, out + (long)b * T * D, D, T, 2);
  }
}

// Round 2
// 202.179 us; speedup vs baseline: 1.5663x; 1.5663x over previous
//
#include <hip/hip_runtime.h>
#include <hip/hip_bf16.h>

typedef unsigned short u16;
typedef __attribute__((ext_vector_type(8))) short short8v;   // 8 bf16 (4 VGPR)
typedef __attribute__((ext_vector_type(4))) float float4v;   // 4 f32 acc

#define BM 128
#define BN 128
#define BK 32

__device__ inline u16 f2b(float f) {
  __hip_bfloat16 h = __float2bfloat16(f);
  union { __hip_bfloat16 h; u16 s; } u;
  u.h = h;
  return u.s;
}

__device__ inline float b2f(u16 s) {
  union { u16 s[2]; float f; } u;
  u.s[0] = 0; u.s[1] = s;
  return u.f;
}

__device__ inline void gload_lds16(const u16* g, u16* l) {
  __builtin_amdgcn_global_load_lds(
      (const __attribute__((address_space(1))) void*)g,
      (__attribute__((address_space(3))) void*)l, 16, 0, 0);
}

// ---------------------------------------------------------------------------
// fp32 -> bf16 conversion (vectorized, grid-stride)
// ---------------------------------------------------------------------------
__global__ __launch_bounds__(256) void cvt_f32_bf16(const float* __restrict__ in,
                                                    u16* __restrict__ out, int n4) {
  for (int i = blockIdx.x * blockDim.x + threadIdx.x; i < n4;
       i += gridDim.x * blockDim.x) {
    float4 v = ((const float4*)in)[i];
    ushort4 o;
    o.x = f2b(v.x); o.y = f2b(v.y); o.z = f2b(v.z); o.w = f2b(v.w);
    ((ushort4*)out)[i] = o;
  }
}

// ---------------------------------------------------------------------------
// gemm_bt: C[m][n] = sum_k A[m][k] * B[n][k]   (both row-major, K contiguous)
// 128x128 tile, BK=32, 4 waves (2x2 of 64x64), mfma_f32_16x16x32_bf16.
// Batched via blockIdx.z with element strides sA/sB/sC.
// causal_mode: 0 = none; 1 = skip tile if n0 > m0+BM (scores);
//              2 = cap K at m0+BM+1 (PV; A must be zero-padded to BK boundary),
//                  tile rows reversed so heavy blocks dispatch first.
// Cf != nullptr -> write fp32, else write bf16 to Cb.
// ---------------------------------------------------------------------------
__global__ __launch_bounds__(256)
void gemm_bt_kernel(const u16* __restrict__ A, int lda, long sA,
                    const u16* __restrict__ B, int ldb, long sB,
                    u16* __restrict__ Cb, float* __restrict__ Cf, int ldc, long sC,
                    int K, int causal_mode) {
  __shared__ __align__(16) u16 lds[2][2][BM * BK];

  const int z = blockIdx.z;
  A += (long)z * sA;
  B += (long)z * sB;

  int bx = blockIdx.x;
  if (causal_mode == 2) bx = gridDim.x - 1 - bx;  // heavy tiles first
  const int m0 = bx * BM;
  const int n0 = blockIdx.y * BN;
  if (causal_mode == 1 && n0 > m0 + BM) return;  // fully masked tile
  int Keff = K;
  if (causal_mode == 2) {
    int cap = m0 + BM + 1;
    if (cap < Keff) Keff = cap;
  }
  const int nk = (Keff + BK - 1) / BK;

  const int tid  = threadIdx.x;
  const int lane = tid & 63;
  const int wid  = tid >> 6;
  const int wr   = wid >> 1;   // 2x2 wave grid, each wave owns 64x64
  const int wc   = wid & 1;

  const u16* ga = A + (long)(m0 + (tid >> 2)) * lda + (tid & 3) * 8;
  const u16* gb = B + (long)(n0 + (tid >> 2)) * ldb + (tid & 3) * 8;

  float4v acc[4][4];
#pragma unroll
  for (int i = 0; i < 4; ++i)
#pragma unroll
    for (int j = 0; j < 4; ++j)
      acc[i][j] = (float4v){0.f, 0.f, 0.f, 0.f};

  auto stage = [&](int b, int kt) {
    const int k0 = kt * BK;
    gload_lds16(ga + k0,            &lds[b][0][tid * 8]);
    gload_lds16(ga + 64 * lda + k0, &lds[b][0][(tid + 256) * 8]);
    gload_lds16(gb + k0,            &lds[b][1][tid * 8]);
    gload_lds16(gb + 64 * ldb + k0, &lds[b][1][(tid + 256) * 8]);
  };

  stage(0, 0);
  int buf = 0;

  const int arow = wr * 64 + (lane & 15);
  const int brow = wc * 64 + (lane & 15);
  const int koff = (lane >> 4) * 8;

  for (int kt = 0; kt < nk; ++kt) {
    __syncthreads();
    if (kt + 1 < nk) stage(buf ^ 1, kt + 1);
    const u16* la = lds[buf][0];
    const u16* lb = lds[buf][1];
    short8v af[4], bfr[4];
#pragma unroll
    for (int mi = 0; mi < 4; ++mi)
      af[mi] = *(const short8v*)&la[(arow + mi * 16) * BK + koff];
#pragma unroll
    for (int ni = 0; ni < 4; ++ni)
      bfr[ni] = *(const short8v*)&lb[(brow + ni * 16) * BK + koff];
#pragma unroll
    for (int mi = 0; mi < 4; ++mi)
#pragma unroll
      for (int ni = 0; ni < 4; ++ni)
        acc[mi][ni] = __builtin_amdgcn_mfma_f32_16x16x32_bf16(
            af[mi], bfr[ni], acc[mi][ni], 0, 0, 0);
    buf ^= 1;
  }

  // C/D layout (m89-verified): col = lane&15, row = (lane>>4)*4 + reg
  u16*   cb = Cb ? Cb + (long)z * sC : nullptr;
  float* cf = Cf ? Cf + (long)z * sC : nullptr;
  const int r0base = m0 + wr * 64 + ((lane >> 4) << 2);
  const int cbase  = n0 + wc * 64 + (lane & 15);
#pragma unroll
  for (int mi = 0; mi < 4; ++mi) {
#pragma unroll
    for (int ni = 0; ni < 4; ++ni) {
      const int r0 = r0base + mi * 16;
      const int c  = cbase + ni * 16;
#pragma unroll
      for (int r = 0; r < 4; ++r) {
        if (cf) cf[(long)(r0 + r) * ldc + c] = acc[mi][ni][r];
        else    cb[(long)(r0 + r) * ldc + c] = f2b(acc[mi][ni][r]);
      }
    }
  }
}

// ---------------------------------------------------------------------------
// masked scaled softmax, in place on bf16 S (one row per block, 4 batches via
// flat grid of B*T blocks). Row i sees j <= i+1; scale = 1/32.
// Each thread owns one 8-column chunk (256 thr * 8 = 2048 = T) in registers.
// Zero-pads P only up to the PV tile-row K cap (m0 + 160).
// ---------------------------------------------------------------------------
__global__ __launch_bounds__(256)
void softmax_kernel(u16* __restrict__ SP, int T) {
  const int  i    = blockIdx.x & (T - 1);
  const long base = (long)blockIdx.x * T;
  const int  nvis = min(i + 2, T);
  const int  capJ = min(T, ((i >> 7) << 7) + BM + BK);  // PV staging extent
  const float scale = 0.03125f;

  __shared__ float red[4];

  const int j0 = threadIdx.x * 8;
  float v[8];
  float m = -INFINITY;
  if (j0 < nvis) {
    short8v raw = *(const short8v*)&SP[base + j0];
#pragma unroll
    for (int e = 0; e < 8; ++e) {
      float f = (j0 + e < nvis) ? b2f((u16)raw[e]) * scale : -INFINITY;
      v[e] = f;
      m = fmaxf(m, f);
    }
  }
#pragma unroll
  for (int o = 32; o; o >>= 1) m = fmaxf(m, __shfl_xor(m, o));
  const int wid = threadIdx.x >> 6;
  if ((threadIdx.x & 63) == 0) red[wid] = m;
  __syncthreads();
  m = fmaxf(fmaxf(red[0], red[1]), fmaxf(red[2], red[3]));
  __syncthreads();

  float s = 0.f;
  if (j0 < nvis) {
#pragma unroll
    for (int e = 0; e < 8; ++e) {
      float p = (j0 + e < nvis) ? __expf(v[e] - m) : 0.f;
      v[e] = p;
      s += p;
    }
  }
#pragma unroll
  for (int o = 32; o; o >>= 1) s += __shfl_xor(s, o);
  if ((threadIdx.x & 63) == 0) red[wid] = s;
  __syncthreads();
  s = red[0] + red[1] + red[2] + red[3];
  const float inv = 1.0f / s;

  if (j0 < capJ) {
    short8v o8;
#pragma unroll
    for (int e = 0; e < 8; ++e)
      o8[e] = (short)f2b((j0 + e < nvis) ? v[e] * inv : 0.f);
    *(short8v*)&SP[base + j0] = o8;
  }
}

// ---------------------------------------------------------------------------
extern "C" void kernel_launch(void* const* d_in, const int* in_sizes, int n_in,
                              void* d_out, int out_size, void* d_ws, size_t ws_size,
                              hipStream_t stream) {
  const float* x  = (const float*)d_in[0];
  const float* Wq = (const float*)d_in[1];
  const float* Wk = (const float*)d_in[2];
  const float* Wv = (const float*)d_in[3];
  float* out = (float*)d_out;

  const int B = 4, T = 2048, D = 1024;
  const int M = B * T;          // 8192
  const long TT = (long)T * T;  // 4 Mi elements

  char* ws = (char*)d_ws;
  u16* qk  = (u16*)(ws);                      // 32 MiB: [8192][2048], q|k
  u16* vt  = (u16*)(ws + (32l << 20));        // 16 MiB: [1024][8192] d-major
  u16* xb  = (u16*)(ws + (48l << 20));        // 16 MiB (dead after vt GEMM)
  u16* wqk = (u16*)(ws + (64l << 20));        //  4 MiB: [2048][1024]
  u16* wv  = (u16*)(ws + (68l << 20));        //  2 MiB
  u16* S   = (u16*)(ws + (48l << 20));        // 32 MiB: 4 x [2048][2048] bf16
                                              //   (overlaps xb/wqk/wv, safe:
                                              //    written only after they die)
  // peak: 80 MiB

  // fp32 -> bf16
  cvt_f32_bf16<<<2048, 256, 0, stream>>>(x,  xb,  (M * D) / 4);
  cvt_f32_bf16<<<512,  256, 0, stream>>>(Wq, wqk,               (D * D) / 4);
  cvt_f32_bf16<<<512,  256, 0, stream>>>(Wk, wqk + (long)D * D, (D * D) / 4);
  cvt_f32_bf16<<<512,  256, 0, stream>>>(Wv, wv,  (D * D) / 4);

  // qk = x @ [Wq;Wk]^T  (8192 x 2048)
  gemm_bt_kernel<<<dim3(M / BM, 2 * D / BN, 1), 256, 0, stream>>>(
      xb, D, 0, wqk, D, 0, qk, nullptr, 2 * D, 0, D, 0);
  // vt = Wv @ x^T  (1024 x 8192, d-major)
  gemm_bt_kernel<<<dim3(D / BM, M / BN, 1), 256, 0, stream>>>(
      wv, D, 0, xb, D, 0, vt, nullptr, M, 0, D, 0);

  // S_b = q_b k_b^T (bf16, tile-skip above diagonal), all batches
  gemm_bt_kernel<<<dim3(T / BM, T / BN, B), 256, 0, stream>>>(
      qk, 2 * D, (long)T * 2 * D,            // A = q_b
      qk + D, 2 * D, (long)T * 2 * D,        // B = k_b
      S, nullptr, T, TT, D, 1);

  // softmax in place (S -> P), all rows of all batches
  softmax_kernel<<<B * T, 256, 0, stream>>>(S, T);

  // O_b = P_b V_b = P_b (vt_b)^T, K capped per tile-row, all batches
  gemm_bt_kernel<<<dim3(T / BM, D / BN, B), 256, 0, stream>>>(
      S, T, TT,                              // A = P_b
      vt, M, T,                              // B = vt columns b*T..
      nullptr, out, D, (long)T * D, T, 2);
}

// Round 3
// 191.895 us; speedup vs baseline: 1.6502x; 1.0536x over previous
//
#include <hip/hip_runtime.h>
#include <hip/hip_bf16.h>

typedef unsigned short u16;
typedef __attribute__((ext_vector_type(8))) short short8v;   // 8 bf16 (4 VGPR)
typedef __attribute__((ext_vector_type(4))) float float4v;   // 4 f32 acc

__device__ inline u16 f2b(float f) {
  __hip_bfloat16 h = __float2bfloat16(f);
  union { __hip_bfloat16 h; u16 s; } u;
  u.h = h;
  return u.s;
}

__device__ inline float b2f(u16 s) {
  union { u16 s[2]; float f; } u;
  u.s[0] = 0; u.s[1] = s;
  return u.f;
}

__device__ inline void gload_lds16(const u16* g, u16* l) {
  __builtin_amdgcn_global_load_lds(
      (const __attribute__((address_space(1))) void*)g,
      (__attribute__((address_space(3))) void*)l, 16, 0, 0);
}

// ---------------------------------------------------------------------------
// fp32 -> bf16 conversion (vectorized, grid-stride)
// ---------------------------------------------------------------------------
__global__ __launch_bounds__(256) void cvt_f32_bf16(const float* __restrict__ in,
                                                    u16* __restrict__ out, int n4) {
  for (int i = blockIdx.x * blockDim.x + threadIdx.x; i < n4;
       i += gridDim.x * blockDim.x) {
    float4 v = ((const float4*)in)[i];
    ushort4 o;
    o.x = f2b(v.x); o.y = f2b(v.y); o.z = f2b(v.z); o.w = f2b(v.w);
    ((ushort4*)out)[i] = o;
  }
}

// ---------------------------------------------------------------------------
// gemm3: C[m][n] = sum_k A[m][k]*B[n][k], both row-major K-contiguous.
// BM=128, BK=64, BN_T in {128,256}. 512 threads = 8 waves (2 Mrow x 4 Ncol),
// per-wave output 64 x BN_T/4. 3-buffer LDS pipeline, counted vmcnt (never 0
// in steady state), raw s_barrier, XOR-swizzled LDS (byte ^= (row&7)<<4) with
// pre-swizzled global source (linear global_load_lds dest), setprio on MFMA.
// MODE: 0 none; 1 skip tile if n0 > m0+128 (scores); 2 cap K at m0+129 (PV,
//       A zero-padded to 64-boundary), bx reversed heavy-first.
// ---------------------------------------------------------------------------
template <int BN_T, int MODE, typename CT>
__global__ __launch_bounds__(512)
void gemm3(const u16* __restrict__ A, int lda, long sA,
           const u16* __restrict__ B, int ldb, long sB,
           CT* __restrict__ C, int ldc, long sC, int K) {
  constexpr int NI = BN_T / 64;            // B-frag cols per wave (per ks)
  constexpr int BJ = BN_T / 64;            // B staging loads per thread
  constexpr int TILE_U16 = (128 + BN_T) * 64;
  constexpr int TILE_BYTES = TILE_U16 * 2;
  __shared__ __align__(16) u16 lds[3 * TILE_U16];

  const int z = blockIdx.z;
  A += (long)z * sA;
  B += (long)z * sB;

  int bx = blockIdx.x;
  if (MODE == 2) bx = gridDim.x - 1 - bx;  // heavy tiles first
  const int m0 = bx * 128;
  const int n0 = blockIdx.y * BN_T;
  if (MODE == 1 && n0 > m0 + 128) return;  // fully masked tile
  int Keff = K;
  if (MODE == 2) Keff = min(m0 + 129, K);
  const int nk = (Keff + 63) >> 6;

  const int tid  = threadIdx.x;
  const int lane = tid & 63;
  const int wid  = tid >> 6;
  const int wr   = wid >> 2;               // 0..1
  const int wc   = wid & 3;                // 0..3

  // ---- staging precompute: chunk c covers LDS bytes [16c,16c+16); the data
  // there must be tile element at swz(16c): row r=c>>3, k-group (c&7)^(r&7).
  const u16* gA[2]; u16* lA[2];
#pragma unroll
  for (int j = 0; j < 2; ++j) {
    int c = tid + j * 512;                 // A chunks: 128*64*2/16 = 1024
    int r = c >> 3;
    int kg = ((c & 7) ^ (r & 7)) * 8;
    gA[j] = A + (long)(m0 + r) * lda + kg;
    lA[j] = &lds[c * 8];
  }
  const u16* gB[BJ]; u16* lB[BJ];
#pragma unroll
  for (int j = 0; j < BJ; ++j) {
    int c = tid + j * 512;                 // B chunks: BN*64*2/16 = BN*8
    int r = c >> 3;
    int kg = ((c & 7) ^ (r & 7)) * 8;
    gB[j] = B + (long)(n0 + r) * ldb + kg;
    lB[j] = &lds[8192 + c * 8];            // B region after A (8192 u16)
  }

  auto stage = [&](int t, int buf) {
    const int k0 = t * 64;
    u16* lbase = &lds[0] + buf * TILE_U16;
    ptrdiff_t dd = lbase - &lds[0];
#pragma unroll
    for (int j = 0; j < 2; ++j) gload_lds16(gA[j] + k0, lA[j] + dd);
#pragma unroll
    for (int j = 0; j < BJ; ++j) gload_lds16(gB[j] + k0, lB[j] + dd);
  };

  // ---- ds_read swizzled byte offsets (tile-local)
  const int rowA = wr * 64 + (lane & 15);
  const int rowB = wc * (BN_T / 4) + (lane & 15);
  const int kb   = (lane >> 4) * 16;
  const int msk  = (lane & 7) << 4;
  const int offA0 = (rowA * 128 + kb) ^ msk;
  const int offA1 = (rowA * 128 + 64 + kb) ^ msk;
  const int offB0 = 16384 + ((rowB * 128 + kb) ^ msk);
  const int offB1 = 16384 + ((rowB * 128 + 64 + kb) ^ msk);

  float4v acc[4][NI];
#pragma unroll
  for (int i = 0; i < 4; ++i)
#pragma unroll
    for (int j = 0; j < NI; ++j)
      acc[i][j] = (float4v){0.f, 0.f, 0.f, 0.f};

  // prologue: stage tiles 0,1,2
  for (int p = 0; p < 3 && p < nk; ++p) stage(p, p);

  const char* ldsc = (const char*)&lds[0];
  int cur = 0;
  for (int t = 0; t < nk; ++t) {
    // counted wait: allow the (up to 2) tiles beyond t to stay in flight
    int a2 = nk - 1 - t;
    if (a2 > 2) a2 = 2;
    if constexpr (BN_T == 256) {
      if (a2 == 2)      asm volatile("s_waitcnt vmcnt(12)" ::: "memory");
      else if (a2 == 1) asm volatile("s_waitcnt vmcnt(6)"  ::: "memory");
      else              asm volatile("s_waitcnt vmcnt(0)"  ::: "memory");
    } else {
      if (a2 == 2)      asm volatile("s_waitcnt vmcnt(8)"  ::: "memory");
      else if (a2 == 1) asm volatile("s_waitcnt vmcnt(4)"  ::: "memory");
      else              asm volatile("s_waitcnt vmcnt(0)"  ::: "memory");
    }
    __builtin_amdgcn_s_barrier();          // tile t visible to all waves
    __builtin_amdgcn_sched_barrier(0);

    const char* bb = ldsc + cur * TILE_BYTES;
    short8v a0[4], a1[4], b0[NI], b1[NI];
#pragma unroll
    for (int mi = 0; mi < 4; ++mi) {
      a0[mi] = *(const short8v*)(bb + offA0 + mi * 2048);
      a1[mi] = *(const short8v*)(bb + offA1 + mi * 2048);
    }
#pragma unroll
    for (int ni = 0; ni < NI; ++ni) {
      b0[ni] = *(const short8v*)(bb + offB0 + ni * 2048);
      b1[ni] = *(const short8v*)(bb + offB1 + ni * 2048);
    }
    asm volatile("s_waitcnt lgkmcnt(0)" ::: "memory");
    __builtin_amdgcn_sched_barrier(0);

    __builtin_amdgcn_s_setprio(1);
#pragma unroll
    for (int mi = 0; mi < 4; ++mi)
#pragma unroll
      for (int ni = 0; ni < NI; ++ni)
        acc[mi][ni] = __builtin_amdgcn_mfma_f32_16x16x32_bf16(
            a0[mi], b0[ni], acc[mi][ni], 0, 0, 0);
#pragma unroll
    for (int mi = 0; mi < 4; ++mi)
#pragma unroll
      for (int ni = 0; ni < NI; ++ni)
        acc[mi][ni] = __builtin_amdgcn_mfma_f32_16x16x32_bf16(
            a1[mi], b1[ni], acc[mi][ni], 0, 0, 0);
    __builtin_amdgcn_s_setprio(0);

    __builtin_amdgcn_s_barrier();          // all waves done reading buf cur
    __builtin_amdgcn_sched_barrier(0);
    if (t + 3 < nk) stage(t + 3, cur);     // overwrite just-freed buffer
    cur = (cur == 2) ? 0 : cur + 1;
  }

  // epilogue: C/D layout col = lane&15, row = (lane>>4)*4 + reg
  CT* c = C + (long)z * sC;
  const int r0base = m0 + wr * 64 + ((lane >> 4) << 2);
  const int cbase  = n0 + wc * (BN_T / 4) + (lane & 15);
#pragma unroll
  for (int mi = 0; mi < 4; ++mi) {
#pragma unroll
    for (int ni = 0; ni < NI; ++ni) {
      const int r0 = r0base + mi * 16;
      const int cc = cbase + ni * 16;
#pragma unroll
      for (int r = 0; r < 4; ++r) {
        float v = acc[mi][ni][r];
        if constexpr (__is_same(CT, float)) c[(long)(r0 + r) * ldc + cc] = v;
        else                                c[(long)(r0 + r) * ldc + cc] = f2b(v);
      }
    }
  }
}

// ---------------------------------------------------------------------------
// masked scaled softmax, in place on bf16 S (one row per block, B*T blocks).
// Row i sees j <= i+1; scale = 1/32. Zero-pads P up to the PV K-extent
// (m0 + 192, 64-aligned for BK=64).
// ---------------------------------------------------------------------------
__global__ __launch_bounds__(256)
void softmax_kernel(u16* __restrict__ SP, int T) {
  const int  i    = blockIdx.x & (T - 1);
  const long base = (long)blockIdx.x * T;
  const int  nvis = min(i + 2, T);
  const int  capJ = min(T, ((i >> 7) << 7) + 192);  // PV staging extent (BK=64)
  const float scale = 0.03125f;

  __shared__ float red[4];

  const int j0 = threadIdx.x * 8;
  float v[8];
  float m = -INFINITY;
  if (j0 < nvis) {
    short8v raw = *(const short8v*)&SP[base + j0];
#pragma unroll
    for (int e = 0; e < 8; ++e) {
      float f = (j0 + e < nvis) ? b2f((u16)raw[e]) * scale : -INFINITY;
      v[e] = f;
      m = fmaxf(m, f);
    }
  }
#pragma unroll
  for (int o = 32; o; o >>= 1) m = fmaxf(m, __shfl_xor(m, o));
  const int wid = threadIdx.x >> 6;
  if ((threadIdx.x & 63) == 0) red[wid] = m;
  __syncthreads();
  m = fmaxf(fmaxf(red[0], red[1]), fmaxf(red[2], red[3]));
  __syncthreads();

  float s = 0.f;
  if (j0 < nvis) {
#pragma unroll
    for (int e = 0; e < 8; ++e) {
      float p = (j0 + e < nvis) ? __expf(v[e] - m) : 0.f;
      v[e] = p;
      s += p;
    }
  }
#pragma unroll
  for (int o = 32; o; o >>= 1) s += __shfl_xor(s, o);
  if ((threadIdx.x & 63) == 0) red[wid] = s;
  __syncthreads();
  s = red[0] + red[1] + red[2] + red[3];
  const float inv = 1.0f / s;

  if (j0 < capJ) {
    short8v o8;
#pragma unroll
    for (int e = 0; e < 8; ++e)
      o8[e] = (short)f2b((j0 + e < nvis) ? v[e] * inv : 0.f);
    *(short8v*)&SP[base + j0] = o8;
  }
}

// ---------------------------------------------------------------------------
extern "C" void kernel_launch(void* const* d_in, const int* in_sizes, int n_in,
                              void* d_out, int out_size, void* d_ws, size_t ws_size,
                              hipStream_t stream) {
  const float* x  = (const float*)d_in[0];
  const float* Wq = (const float*)d_in[1];
  const float* Wk = (const float*)d_in[2];
  const float* Wv = (const float*)d_in[3];
  float* out = (float*)d_out;

  const int B = 4, T = 2048, D = 1024;
  const int M = B * T;          // 8192
  const long TT = (long)T * T;  // 4 Mi elements

  char* ws = (char*)d_ws;
  u16* qk  = (u16*)(ws);                      // 32 MiB: [8192][2048], q|k
  u16* vt  = (u16*)(ws + (32l << 20));        // 16 MiB: [1024][8192] d-major
  u16* xb  = (u16*)(ws + (48l << 20));        // 16 MiB (dead after vt GEMM)
  u16* wqk = (u16*)(ws + (64l << 20));        //  4 MiB: [2048][1024]
  u16* wv  = (u16*)(ws + (68l << 20));        //  2 MiB
  u16* S   = (u16*)(ws + (48l << 20));        // 32 MiB: 4 x [2048][2048] bf16
                                              //   (overlaps xb/wqk/wv; written
                                              //    only after they are dead)
  // peak: 80 MiB

  // fp32 -> bf16
  cvt_f32_bf16<<<2048, 256, 0, stream>>>(x,  xb,  (M * D) / 4);
  cvt_f32_bf16<<<512,  256, 0, stream>>>(Wq, wqk,               (D * D) / 4);
  cvt_f32_bf16<<<512,  256, 0, stream>>>(Wk, wqk + (long)D * D, (D * D) / 4);
  cvt_f32_bf16<<<512,  256, 0, stream>>>(Wv, wv,  (D * D) / 4);

  // qk = x @ [Wq;Wk]^T  (8192 x 2048): grid 64x8, BN=256
  gemm3<256, 0, u16><<<dim3(M / 128, 2 * D / 256, 1), 512, 0, stream>>>(
      xb, D, 0, wqk, D, 0, qk, 2 * D, 0, D);
  // vt = Wv @ x^T  (1024 x 8192, d-major): grid 8x32, BN=256
  gemm3<256, 0, u16><<<dim3(D / 128, M / 256, 1), 512, 0, stream>>>(
      wv, D, 0, xb, D, 0, vt, M, 0, D);

  // S_b = q_b k_b^T (bf16, tile-skip above diagonal): grid 16x16x4, BN=128
  gemm3<128, 1, u16><<<dim3(T / 128, T / 128, B), 512, 0, stream>>>(
      qk, 2 * D, (long)T * 2 * D,
      qk + D, 2 * D, (long)T * 2 * D,
      S, T, TT, D);

  // softmax in place (S -> P), all rows of all batches
  softmax_kernel<<<B * T, 256, 0, stream>>>(S, T);

  // O_b = P_b V_b = P_b (vt_b)^T, K capped per tile-row: grid 16x8x4, BN=128
  gemm3<128, 2, float><<<dim3(T / 128, D / 128, B), 512, 0, stream>>>(
      S, T, TT,
      vt, M, T,
      out, D, (long)T * D, T);
}

// Round 4
// 175.887 us; speedup vs baseline: 1.8004x; 1.0910x over previous
//
#include <hip/hip_runtime.h>
#include <hip/hip_bf16.h>

typedef unsigned short u16;
typedef __attribute__((ext_vector_type(8))) short short8v;   // 8 bf16 (4 VGPR)
typedef __attribute__((ext_vector_type(4))) float float4v;   // 4 f32 acc

__device__ inline u16 f2b(float f) {
  __hip_bfloat16 h = __float2bfloat16(f);
  union { __hip_bfloat16 h; u16 s; } u;
  u.h = h;
  return u.s;
}

__device__ inline float b2f(u16 s) {
  union { u16 s[2]; float f; } u;
  u.s[0] = 0; u.s[1] = s;
  return u.f;
}

__device__ inline void gload_lds16(const u16* g, u16* l) {
  __builtin_amdgcn_global_load_lds(
      (const __attribute__((address_space(1))) void*)g,
      (__attribute__((address_space(3))) void*)l, 16, 0, 0);
}

// ---------------------------------------------------------------------------
// fp32 -> bf16 conversion (vectorized, grid-stride)
// ---------------------------------------------------------------------------
__global__ __launch_bounds__(256) void cvt_f32_bf16(const float* __restrict__ in,
                                                    u16* __restrict__ out, int n4) {
  for (int i = blockIdx.x * blockDim.x + threadIdx.x; i < n4;
       i += gridDim.x * blockDim.x) {
    float4 v = ((const float4*)in)[i];
    ushort4 o;
    o.x = f2b(v.x); o.y = f2b(v.y); o.z = f2b(v.z); o.w = f2b(v.w);
    ((ushort4*)out)[i] = o;
  }
}

// ---------------------------------------------------------------------------
// gemm4: C[m][n] = sum_k A[m][k]*B[n][k], both row-major K-contiguous.
// BM=256, BN=128, BK=64. 512 threads = 8 waves (4M x 2N), 64x64 per wave.
// 3-buffer LDS pipeline (144 KB), counted vmcnt(6) at iteration top (one
// full tile of loads stays in flight; never drains mid-loop). Two phases
// per K-tile (one per 32-k slice), each: {8 ds_read_b128 | issue 3 staging
// loads for tile t+2 -> s_barrier -> lgkmcnt(0)+sched_barrier ->
// setprio(1) 16 MFMA setprio(0)}. XOR swizzle byte^=(row&7)<<4 via
// pre-swizzled global source (linear global_load_lds dest) + swizzled reads.
// MODE: 0 none; 1 skip tile if n0 > m0+256 (scores); 2 cap K at m0+257
//       (PV; A zero-padded to staged extent), bx reversed heavy-first.
// ---------------------------------------------------------------------------
template <int MODE, typename CT>
__global__ __launch_bounds__(512)
void gemm4(const u16* __restrict__ A, int lda, long sA,
           const u16* __restrict__ B, int ldb, long sB,
           CT* __restrict__ C, int ldc, long sC, int K) {
  constexpr int BM = 256, BN = 128, BK = 64;
  constexpr int TILE_U16 = (BM + BN) * BK;         // 24576
  constexpr int TILE_BYTES = TILE_U16 * 2;         // 49152
  __shared__ __align__(16) u16 lds[3 * TILE_U16];  // 144 KiB

  const int z = blockIdx.z;
  A += (long)z * sA;
  B += (long)z * sB;

  int bx = blockIdx.x;
  if (MODE == 2) bx = gridDim.x - 1 - bx;          // heavy tiles first
  const int m0 = bx * BM;
  const int n0 = blockIdx.y * BN;
  if (MODE == 1 && n0 > m0 + BM) return;           // fully masked tile
  int Keff = K;
  if (MODE == 2) Keff = min(m0 + BM + 1, K);
  const int nk = (Keff + BK - 1) >> 6;

  const int tid  = threadIdx.x;
  const int lane = tid & 63;
  const int wid  = tid >> 6;
  const int wr   = wid >> 1;    // 0..3 (M)
  const int wc   = wid & 1;     // 0..1 (N)

  // staging map: chunk c (16B at LDS byte 16c): row r=c>>3, physical slot
  // c&7 holds logical k-slot (c&7)^(r&7)  => global k-offset ((c&7)^(r&7))*8.
  const u16* gA[4]; int oA[4];
#pragma unroll
  for (int j = 0; j < 4; ++j) {
    int c = tid + j * 512;                         // 2048 A chunks
    int r = c >> 3;
    int kg = ((c & 7) ^ (r & 7)) * 8;
    gA[j] = A + (long)(m0 + r) * lda + kg;
    oA[j] = c * 8;
  }
  const u16* gB[2]; int oB[2];
#pragma unroll
  for (int j = 0; j < 2; ++j) {
    int c = tid + j * 512;                         // 1024 B chunks
    int r = c >> 3;
    int kg = ((c & 7) ^ (r & 7)) * 8;
    gB[j] = B + (long)(n0 + r) * ldb + kg;
    oB[j] = BM * BK + c * 8;
  }

  auto stageA3 = [&](int t, int buf) {
    const int k0 = t * BK;
    u16* base = lds + buf * TILE_U16;
    gload_lds16(gA[0] + k0, base + oA[0]);
    gload_lds16(gA[1] + k0, base + oA[1]);
    gload_lds16(gA[2] + k0, base + oA[2]);
  };
  auto stageRest = [&](int t, int buf) {
    const int k0 = t * BK;
    u16* base = lds + buf * TILE_U16;
    gload_lds16(gA[3] + k0, base + oA[3]);
    gload_lds16(gB[0] + k0, base + oB[0]);
    gload_lds16(gB[1] + k0, base + oB[1]);
  };

  // ds_read byte offsets (within buffer), swizzled
  const int rowA = wr * 64 + (lane & 15);
  const int rowB = wc * 64 + (lane & 15);
  const int msk  = (lane & 7) << 4;
  const int kl   = (lane >> 4) * 16;
  const int offA[2] = { rowA * 128 + ((kl) ^ msk),
                        rowA * 128 + ((64 + kl) ^ msk) };
  const int offB[2] = { 2 * BM * BK + rowB * 128 + ((kl) ^ msk),
                        2 * BM * BK + rowB * 128 + ((64 + kl) ^ msk) };

  float4v acc[4][4];
#pragma unroll
  for (int i = 0; i < 4; ++i)
#pragma unroll
    for (int j = 0; j < 4; ++j)
      acc[i][j] = (float4v){0.f, 0.f, 0.f, 0.f};

  // prologue: stage tiles 0,1
  stageA3(0, 0); stageRest(0, 0);
  if (nk > 1) { stageA3(1, 1); stageRest(1, 1); }

  int cur = 0;
  for (int t = 0; t < nk; ++t) {
    if (t + 1 < nk) asm volatile("s_waitcnt vmcnt(6)" ::: "memory");
    else            asm volatile("s_waitcnt vmcnt(0)" ::: "memory");
    __builtin_amdgcn_s_barrier();                  // tile t visible to all
    __builtin_amdgcn_sched_barrier(0);

    const char* bb = (const char*)lds + cur * TILE_BYTES;
    const int  nxt2 = (cur >= 1) ? cur - 1 : 2;    // (cur+2)%3, freed last iter
    const bool st   = (t + 2 < nk);

#pragma unroll
    for (int ks = 0; ks < 2; ++ks) {
      short8v a[4], b[4];
#pragma unroll
      for (int mi = 0; mi < 4; ++mi)
        a[mi] = *(const short8v*)(bb + offA[ks] + mi * 2048);
#pragma unroll
      for (int ni = 0; ni < 4; ++ni)
        b[ni] = *(const short8v*)(bb + offB[ks] + ni * 2048);
      if (ks == 0) { if (st) stageA3(t + 2, nxt2); }
      else         { if (st) stageRest(t + 2, nxt2); }
      __builtin_amdgcn_s_barrier();                // phase sync (role split)
      asm volatile("s_waitcnt lgkmcnt(0)" ::: "memory");
      __builtin_amdgcn_sched_barrier(0);
      __builtin_amdgcn_s_setprio(1);
#pragma unroll
      for (int mi = 0; mi < 4; ++mi)
#pragma unroll
        for (int ni = 0; ni < 4; ++ni)
          acc[mi][ni] = __builtin_amdgcn_mfma_f32_16x16x32_bf16(
              a[mi], b[ni], acc[mi][ni], 0, 0, 0);
      __builtin_amdgcn_s_setprio(0);
    }
    cur = (cur < 2) ? cur + 1 : 0;
  }

  // epilogue: C/D layout col = lane&15, row = (lane>>4)*4 + reg
  CT* c = C + (long)z * sC;
  const int r0base = m0 + wr * 64 + ((lane >> 4) << 2);
  const int cbase  = n0 + wc * 64 + (lane & 15);
#pragma unroll
  for (int mi = 0; mi < 4; ++mi) {
#pragma unroll
    for (int ni = 0; ni < 4; ++ni) {
      const int r0 = r0base + mi * 16;
      const int cc = cbase + ni * 16;
#pragma unroll
      for (int r = 0; r < 4; ++r) {
        float v = acc[mi][ni][r];
        if constexpr (__is_same(CT, float)) c[(long)(r0 + r) * ldc + cc] = v;
        else                                c[(long)(r0 + r) * ldc + cc] = f2b(v);
      }
    }
  }
}

// ---------------------------------------------------------------------------
// masked scaled softmax, in place on bf16 S (one row per block, B*T blocks).
// Row i sees j <= i+1; scale = 1/32. Zero-pads P up to the PV staged extent
// (m-tile base + 320, BM=256/BK=64).
// ---------------------------------------------------------------------------
__global__ __launch_bounds__(256)
void softmax_kernel(u16* __restrict__ SP, int T) {
  const int  i    = blockIdx.x & (T - 1);
  const long base = (long)blockIdx.x * T;
  const int  nvis = min(i + 2, T);
  const int  capJ = min(T, ((i >> 8) << 8) + 320);  // PV staging extent
  const float scale = 0.03125f;

  __shared__ float red[4];

  const int j0 = threadIdx.x * 8;
  float v[8];
  float m = -INFINITY;
  if (j0 < nvis) {
    short8v raw = *(const short8v*)&SP[base + j0];
#pragma unroll
    for (int e = 0; e < 8; ++e) {
      float f = (j0 + e < nvis) ? b2f((u16)raw[e]) * scale : -INFINITY;
      v[e] = f;
      m = fmaxf(m, f);
    }
  }
#pragma unroll
  for (int o = 32; o; o >>= 1) m = fmaxf(m, __shfl_xor(m, o));
  const int wid = threadIdx.x >> 6;
  if ((threadIdx.x & 63) == 0) red[wid] = m;
  __syncthreads();
  m = fmaxf(fmaxf(red[0], red[1]), fmaxf(red[2], red[3]));
  __syncthreads();

  float s = 0.f;
  if (j0 < nvis) {
#pragma unroll
    for (int e = 0; e < 8; ++e) {
      float p = (j0 + e < nvis) ? __expf(v[e] - m) : 0.f;
      v[e] = p;
      s += p;
    }
  }
#pragma unroll
  for (int o = 32; o; o >>= 1) s += __shfl_xor(s, o);
  if ((threadIdx.x & 63) == 0) red[wid] = s;
  __syncthreads();
  s = red[0] + red[1] + red[2] + red[3];
  const float inv = 1.0f / s;

  if (j0 < capJ) {
    short8v o8;
#pragma unroll
    for (int e = 0; e < 8; ++e)
      o8[e] = (short)f2b((j0 + e < nvis) ? v[e] * inv : 0.f);
    *(short8v*)&SP[base + j0] = o8;
  }
}

// ---------------------------------------------------------------------------
extern "C" void kernel_launch(void* const* d_in, const int* in_sizes, int n_in,
                              void* d_out, int out_size, void* d_ws, size_t ws_size,
                              hipStream_t stream) {
  const float* x  = (const float*)d_in[0];
  const float* Wq = (const float*)d_in[1];
  const float* Wk = (const float*)d_in[2];
  const float* Wv = (const float*)d_in[3];
  float* out = (float*)d_out;

  const int B = 4, T = 2048, D = 1024;
  const int M = B * T;          // 8192
  const long TT = (long)T * T;  // 4 Mi elements

  char* ws = (char*)d_ws;
  u16* qk  = (u16*)(ws);                      // 32 MiB: [8192][2048], q|k
  u16* vt  = (u16*)(ws + (32l << 20));        // 16 MiB: [1024][8192] d-major
  u16* xb  = (u16*)(ws + (48l << 20));        // 16 MiB (dead after vt GEMM)
  u16* wqk = (u16*)(ws + (64l << 20));        //  4 MiB: [2048][1024]
  u16* wv  = (u16*)(ws + (68l << 20));        //  2 MiB
  u16* S   = (u16*)(ws + (48l << 20));        // 32 MiB: 4 x [2048][2048] bf16
                                              //   (overlaps xb/wqk/wv; written
                                              //    only after they are dead)
  // peak: 80 MiB

  // fp32 -> bf16
  cvt_f32_bf16<<<2048, 256, 0, stream>>>(x,  xb,  (M * D) / 4);
  cvt_f32_bf16<<<512,  256, 0, stream>>>(Wq, wqk,               (D * D) / 4);
  cvt_f32_bf16<<<512,  256, 0, stream>>>(Wk, wqk + (long)D * D, (D * D) / 4);
  cvt_f32_bf16<<<512,  256, 0, stream>>>(Wv, wv,  (D * D) / 4);

  // qk = x @ [Wq;Wk]^T  (8192 x 2048): grid 32x16
  gemm4<0, u16><<<dim3(M / 256, 2 * D / 128, 1), 512, 0, stream>>>(
      xb, D, 0, wqk, D, 0, qk, 2 * D, 0, D);
  // vt = Wv @ x^T  (1024 x 8192, d-major): grid 4x64
  gemm4<0, u16><<<dim3(D / 256, M / 128, 1), 512, 0, stream>>>(
      wv, D, 0, xb, D, 0, vt, M, 0, D);

  // S_b = q_b k_b^T (bf16, tile-skip above diagonal): grid 8x16x4
  gemm4<1, u16><<<dim3(T / 256, T / 128, B), 512, 0, stream>>>(
      qk, 2 * D, (long)T * 2 * D,
      qk + D, 2 * D, (long)T * 2 * D,
      S, T, TT, D);

  // softmax in place (S -> P), all rows of all batches
  softmax_kernel<<<B * T, 256, 0, stream>>>(S, T);

  // O_b = P_b V_b = P_b (vt_b)^T, K capped per tile-row: grid 8x8x4
  gemm4<2, float><<<dim3(T / 256, D / 128, B), 512, 0, stream>>>(
      S, T, TT,
      vt, M, T,
      out, D, (long)T * D, T);
}

// Round 5
// 172.553 us; speedup vs baseline: 1.8352x; 1.0193x over previous
//
#include <hip/hip_runtime.h>
#include <hip/hip_bf16.h>

typedef unsigned short u16;
typedef __attribute__((ext_vector_type(8))) short short8v;   // 8 bf16 (4 VGPR)
typedef __attribute__((ext_vector_type(4))) float float4v;   // 4 f32 acc

__device__ inline u16 f2b(float f) {
  __hip_bfloat16 h = __float2bfloat16(f);
  union { __hip_bfloat16 h; u16 s; } u;
  u.h = h;
  return u.s;
}

__device__ inline float b2f(u16 s) {
  union { u16 s[2]; float f; } u;
  u.s[0] = 0; u.s[1] = s;
  return u.f;
}

__device__ inline void gload_lds16(const u16* g, u16* l) {
  __builtin_amdgcn_global_load_lds(
      (const __attribute__((address_space(1))) void*)g,
      (__attribute__((address_space(3))) void*)l, 16, 0, 0);
}

// ---------------------------------------------------------------------------
// fp32 -> bf16 conversion (vectorized, grid-stride)
// ---------------------------------------------------------------------------
__global__ __launch_bounds__(256) void cvt_f32_bf16(const float* __restrict__ in,
                                                    u16* __restrict__ out, int n4) {
  for (int i = blockIdx.x * blockDim.x + threadIdx.x; i < n4;
       i += gridDim.x * blockDim.x) {
    float4 v = ((const float4*)in)[i];
    ushort4 o;
    o.x = f2b(v.x); o.y = f2b(v.y); o.z = f2b(v.z); o.w = f2b(v.w);
    ((ushort4*)out)[i] = o;
  }
}

// ---------------------------------------------------------------------------
// gemm5: C[m][n] = sum_k A[m][k]*B[n][k], both row-major K-contiguous.
// BM = 2*WM, BN = 256, BK = 64. 512 threads = 8 waves (2M x 4N), per-wave
// output WM x 64. Double-buffered LDS; per K-tile: all of tile t+1's staging
// issued at phase 0 (max slack), counted drain (vmcnt(0) on only-next-tile
// loads) + barrier at iteration end. Phases: {ds_read frags -> s_barrier ->
// lgkmcnt(0)+sched_barrier -> setprio(1) 16 MFMA setprio(0) -> s_barrier}.
// XOR swizzle byte^=(row&7)<<4 via pre-swizzled global source (linear
// global_load_lds dest) + swizzled ds_reads (0 bank conflicts, r3/r4).
// WM=128 -> 4 phases/K-tile (A-halves x 2 kslices); WM=64 -> 2 phases.
// MODE: 0 none; 1 skip tile if n0 > m0+BM (scores); 2 cap K at m0+BM+1
//       (PV; A zero-padded to staged extent), bx reversed heavy-first.
// ---------------------------------------------------------------------------
template <int WM, int MODE, typename CT>
__global__ __launch_bounds__(512)
void gemm5(const u16* __restrict__ A, int lda, long sA,
           const u16* __restrict__ B, int ldb, long sB,
           CT* __restrict__ C, int ldc, long sC, int K) {
  constexpr int BM = 2 * WM;
  constexpr int BN = 256;
  constexpr int A_U16 = BM * 64;                 // u16 elems of A region
  constexpr int TILE_U16 = (BM + BN) * 64;
  constexpr int TILE_BYTES = TILE_U16 * 2;
  constexpr int LA = BM / 64;                    // A staging loads / thread
  constexpr int LB = 4;                          // B staging loads / thread
  __shared__ __align__(16) u16 lds[2 * TILE_U16];

  const int z = blockIdx.z;
  A += (long)z * sA;
  B += (long)z * sB;

  int bx = blockIdx.x;
  if (MODE == 2) bx = gridDim.x - 1 - bx;        // heavy tiles first
  const int m0 = bx * BM;
  const int n0 = blockIdx.y * BN;
  if (MODE == 1 && n0 > m0 + BM) return;         // fully masked tile
  int Keff = K;
  if (MODE == 2) Keff = min(m0 + BM + 1, K);
  const int nk = (Keff + 63) >> 6;

  const int tid  = threadIdx.x;
  const int lane = tid & 63;
  const int wid  = tid >> 6;
  const int wr   = wid >> 2;                     // 0..1 (M)
  const int wc   = wid & 3;                      // 0..3 (N)

  // staging map: chunk c -> LDS bytes [16c,16c+16): row r=c>>3, physical
  // 16B slot (c&7) holds logical k-slot (c&7)^(r&7) -> k-offset *8 elems.
  const u16* gsrc[LA + LB];
  int loff[LA + LB];
#pragma unroll
  for (int j = 0; j < LA; ++j) {
    int c = tid + j * 512;
    int r = c >> 3;
    int kg = ((c & 7) ^ (r & 7)) * 8;
    gsrc[j] = A + (long)(m0 + r) * lda + kg;
    loff[j] = c * 8;
  }
#pragma unroll
  for (int j = 0; j < LB; ++j) {
    int c = tid + j * 512;
    int r = c >> 3;
    int kg = ((c & 7) ^ (r & 7)) * 8;
    gsrc[LA + j] = B + (long)(n0 + r) * ldb + kg;
    loff[LA + j] = A_U16 + c * 8;
  }

  // ds_read swizzled byte offsets
  const int kl  = (lane >> 4) * 16;
  const int swz = (lane & 7) << 4;
  const int kx0 = kl ^ swz;
  const int kx1 = (64 + kl) ^ swz;
  const int abase = (wr * WM + (lane & 15)) * 128;
  const int bbase = BM * 128 + (wc * 64 + (lane & 15)) * 128;

  float4v acc[WM / 16][4];
#pragma unroll
  for (int i = 0; i < WM / 16; ++i)
#pragma unroll
    for (int j = 0; j < 4; ++j)
      acc[i][j] = (float4v){0.f, 0.f, 0.f, 0.f};

#define STAGE_ALL(T_, DST_)                                                 \
  {                                                                         \
    _Pragma("unroll")                                                       \
    for (int s = 0; s < LA + LB; ++s)                                       \
      gload_lds16(gsrc[s] + (long)(T_) * 64, (DST_) + loff[s]);             \
  }

  // prologue: stage tile 0 into buf 0
  STAGE_ALL(0, lds);
  asm volatile("s_waitcnt vmcnt(0)" ::: "memory");
  __builtin_amdgcn_s_barrier();

  int cur = 0;
  for (int t = 0; t < nk; ++t) {
    const char* bb = (const char*)lds + cur * TILE_BYTES;
    u16* sb = lds + (cur ^ 1) * TILE_U16;
    const bool st = (t + 1 < nk);
    short8v b[4];

    // ---- phase 0: kslice 0, A-frags 0..3 (+B), stage ALL of tile t+1
    {
      short8v a[4];
#pragma unroll
      for (int mi = 0; mi < 4; ++mi)
        a[mi] = *(const short8v*)(bb + abase + mi * 2048 + kx0);
#pragma unroll
      for (int ni = 0; ni < 4; ++ni)
        b[ni] = *(const short8v*)(bb + bbase + ni * 2048 + kx0);
      if (st) STAGE_ALL(t + 1, sb);
      __builtin_amdgcn_s_barrier();
      asm volatile("s_waitcnt lgkmcnt(0)" ::: "memory");
      __builtin_amdgcn_sched_barrier(0);
      __builtin_amdgcn_s_setprio(1);
#pragma unroll
      for (int mi = 0; mi < 4; ++mi)
#pragma unroll
        for (int ni = 0; ni < 4; ++ni)
          acc[mi][ni] = __builtin_amdgcn_mfma_f32_16x16x32_bf16(
              a[mi], b[ni], acc[mi][ni], 0, 0, 0);
      __builtin_amdgcn_s_setprio(0);
      __builtin_amdgcn_s_barrier();
    }
    if constexpr (WM == 128) {
      // ---- phase 1: kslice 0, A-frags 4..7
      {
        short8v a[4];
#pragma unroll
        for (int mi = 0; mi < 4; ++mi)
          a[mi] = *(const short8v*)(bb + abase + 8192 + mi * 2048 + kx0);
        __builtin_amdgcn_s_barrier();
        asm volatile("s_waitcnt lgkmcnt(0)" ::: "memory");
        __builtin_amdgcn_sched_barrier(0);
        __builtin_amdgcn_s_setprio(1);
#pragma unroll
        for (int mi = 0; mi < 4; ++mi)
#pragma unroll
          for (int ni = 0; ni < 4; ++ni)
            acc[4 + mi][ni] = __builtin_amdgcn_mfma_f32_16x16x32_bf16(
                a[mi], b[ni], acc[4 + mi][ni], 0, 0, 0);
        __builtin_amdgcn_s_setprio(0);
        __builtin_amdgcn_s_barrier();
      }
      // ---- phase 2: kslice 1, A-frags 0..3 (+B)
      {
        short8v a[4];
#pragma unroll
        for (int mi = 0; mi < 4; ++mi)
          a[mi] = *(const short8v*)(bb + abase + mi * 2048 + kx1);
#pragma unroll
        for (int ni = 0; ni < 4; ++ni)
          b[ni] = *(const short8v*)(bb + bbase + ni * 2048 + kx1);
        __builtin_amdgcn_s_barrier();
        asm volatile("s_waitcnt lgkmcnt(0)" ::: "memory");
        __builtin_amdgcn_sched_barrier(0);
        __builtin_amdgcn_s_setprio(1);
#pragma unroll
        for (int mi = 0; mi < 4; ++mi)
#pragma unroll
          for (int ni = 0; ni < 4; ++ni)
            acc[mi][ni] = __builtin_amdgcn_mfma_f32_16x16x32_bf16(
                a[mi], b[ni], acc[mi][ni], 0, 0, 0);
        __builtin_amdgcn_s_setprio(0);
        __builtin_amdgcn_s_barrier();
      }
      // ---- phase 3: kslice 1, A-frags 4..7 (+iter-end drain)
      {
        short8v a[4];
#pragma unroll
        for (int mi = 0; mi < 4; ++mi)
          a[mi] = *(const short8v*)(bb + abase + 8192 + mi * 2048 + kx1);
        __builtin_amdgcn_s_barrier();
        asm volatile("s_waitcnt lgkmcnt(0)" ::: "memory");
        __builtin_amdgcn_sched_barrier(0);
        __builtin_amdgcn_s_setprio(1);
#pragma unroll
        for (int mi = 0; mi < 4; ++mi)
#pragma unroll
          for (int ni = 0; ni < 4; ++ni)
            acc[4 + mi][ni] = __builtin_amdgcn_mfma_f32_16x16x32_bf16(
                a[mi], b[ni], acc[4 + mi][ni], 0, 0, 0);
        __builtin_amdgcn_s_setprio(0);
        asm volatile("s_waitcnt vmcnt(0)" ::: "memory");  // only t+1's loads
        __builtin_amdgcn_s_barrier();
      }
    } else {
      // ---- phase 1 (WM=64): kslice 1 (+iter-end drain)
      {
        short8v a[4];
#pragma unroll
        for (int mi = 0; mi < 4; ++mi)
          a[mi] = *(const short8v*)(bb + abase + mi * 2048 + kx1);
#pragma unroll
        for (int ni = 0; ni < 4; ++ni)
          b[ni] = *(const short8v*)(bb + bbase + ni * 2048 + kx1);
        __builtin_amdgcn_s_barrier();
        asm volatile("s_waitcnt lgkmcnt(0)" ::: "memory");
        __builtin_amdgcn_sched_barrier(0);
        __builtin_amdgcn_s_setprio(1);
#pragma unroll
        for (int mi = 0; mi < 4; ++mi)
#pragma unroll
          for (int ni = 0; ni < 4; ++ni)
            acc[mi][ni] = __builtin_amdgcn_mfma_f32_16x16x32_bf16(
                a[mi], b[ni], acc[mi][ni], 0, 0, 0);
        __builtin_amdgcn_s_setprio(0);
        asm volatile("s_waitcnt vmcnt(0)" ::: "memory");  // only t+1's loads
        __builtin_amdgcn_s_barrier();
      }
    }
    cur ^= 1;
  }
#undef STAGE_ALL

  // epilogue: C/D layout col = lane&15, row = (lane>>4)*4 + reg
  CT* c = C + (long)z * sC;
  const int r0base = m0 + wr * WM + ((lane >> 4) << 2);
  const int cbase  = n0 + wc * 64 + (lane & 15);
#pragma unroll
  for (int mi = 0; mi < WM / 16; ++mi) {
#pragma unroll
    for (int ni = 0; ni < 4; ++ni) {
      const int r0 = r0base + mi * 16;
      const int cc = cbase + ni * 16;
#pragma unroll
      for (int r = 0; r < 4; ++r) {
        float v = acc[mi][ni][r];
        if constexpr (__is_same(CT, float)) c[(long)(r0 + r) * ldc + cc] = v;
        else                                c[(long)(r0 + r) * ldc + cc] = f2b(v);
      }
    }
  }
}

// ---------------------------------------------------------------------------
// masked scaled softmax, in place on bf16 S (one row per block, B*T blocks).
// Row i sees j <= i+1; scale = 1/32. Zero-pads P up to the PV staged extent
// (tile base + 192, BM=128/BK=64).
// ---------------------------------------------------------------------------
__global__ __launch_bounds__(256)
void softmax_kernel(u16* __restrict__ SP, int T) {
  const int  i    = blockIdx.x & (T - 1);
  const long base = (long)blockIdx.x * T;
  const int  nvis = min(i + 2, T);
  const int  capJ = min(T, ((i >> 7) << 7) + 192);  // PV staging extent
  const float scale = 0.03125f;

  __shared__ float red[4];

  const int j0 = threadIdx.x * 8;
  float v[8];
  float m = -INFINITY;
  if (j0 < nvis) {
    short8v raw = *(const short8v*)&SP[base + j0];
#pragma unroll
    for (int e = 0; e < 8; ++e) {
      float f = (j0 + e < nvis) ? b2f((u16)raw[e]) * scale : -INFINITY;
      v[e] = f;
      m = fmaxf(m, f);
    }
  }
#pragma unroll
  for (int o = 32; o; o >>= 1) m = fmaxf(m, __shfl_xor(m, o));
  const int wid = threadIdx.x >> 6;
  if ((threadIdx.x & 63) == 0) red[wid] = m;
  __syncthreads();
  m = fmaxf(fmaxf(red[0], red[1]), fmaxf(red[2], red[3]));
  __syncthreads();

  float s = 0.f;
  if (j0 < nvis) {
#pragma unroll
    for (int e = 0; e < 8; ++e) {
      float p = (j0 + e < nvis) ? __expf(v[e] - m) : 0.f;
      v[e] = p;
      s += p;
    }
  }
#pragma unroll
  for (int o = 32; o; o >>= 1) s += __shfl_xor(s, o);
  if ((threadIdx.x & 63) == 0) red[wid] = s;
  __syncthreads();
  s = red[0] + red[1] + red[2] + red[3];
  const float inv = 1.0f / s;

  if (j0 < capJ) {
    short8v o8;
#pragma unroll
    for (int e = 0; e < 8; ++e)
      o8[e] = (short)f2b((j0 + e < nvis) ? v[e] * inv : 0.f);
    *(short8v*)&SP[base + j0] = o8;
  }
}

// ---------------------------------------------------------------------------
extern "C" void kernel_launch(void* const* d_in, const int* in_sizes, int n_in,
                              void* d_out, int out_size, void* d_ws, size_t ws_size,
                              hipStream_t stream) {
  const float* x  = (const float*)d_in[0];
  const float* Wq = (const float*)d_in[1];
  const float* Wk = (const float*)d_in[2];
  const float* Wv = (const float*)d_in[3];
  float* out = (float*)d_out;

  const int B = 4, T = 2048, D = 1024;
  const int M = B * T;          // 8192
  const long TT = (long)T * T;  // 4 Mi elements

  char* ws = (char*)d_ws;
  u16* qk  = (u16*)(ws);                      // 32 MiB: [8192][2048], q|k
  u16* vt  = (u16*)(ws + (32l << 20));        // 16 MiB: [1024][8192] d-major
  u16* xb  = (u16*)(ws + (48l << 20));        // 16 MiB (dead after vt GEMM)
  u16* wqk = (u16*)(ws + (64l << 20));        //  4 MiB: [2048][1024]
  u16* wv  = (u16*)(ws + (68l << 20));        //  2 MiB
  u16* S   = (u16*)(ws + (48l << 20));        // 32 MiB: 4 x [2048][2048] bf16
                                              //   (overlaps xb/wqk/wv; written
                                              //    only after they are dead)
  // peak: 80 MiB

  // fp32 -> bf16
  cvt_f32_bf16<<<2048, 256, 0, stream>>>(x,  xb,  (M * D) / 4);
  cvt_f32_bf16<<<512,  256, 0, stream>>>(Wq, wqk,               (D * D) / 4);
  cvt_f32_bf16<<<512,  256, 0, stream>>>(Wk, wqk + (long)D * D, (D * D) / 4);
  cvt_f32_bf16<<<512,  256, 0, stream>>>(Wv, wv,  (D * D) / 4);

  // qk = x @ [Wq;Wk]^T  (8192 x 2048): 256x256 tiles, grid 32x8 = 256 blocks
  gemm5<128, 0, u16><<<dim3(M / 256, 2 * D / 256, 1), 512, 0, stream>>>(
      xb, D, 0, wqk, D, 0, qk, 2 * D, 0, D);
  // vt = Wv @ x^T  (1024 x 8192): 128x256 tiles, grid 8x32 = 256 blocks
  gemm5<64, 0, u16><<<dim3(D / 128, M / 256, 1), 512, 0, stream>>>(
      wv, D, 0, xb, D, 0, vt, M, 0, D);

  // S_b = q_b k_b^T (bf16, tile-skip): 128x256 tiles, grid 16x8x4, 316 live
  gemm5<64, 1, u16><<<dim3(T / 128, T / 256, B), 512, 0, stream>>>(
      qk, 2 * D, (long)T * 2 * D,
      qk + D, 2 * D, (long)T * 2 * D,
      S, T, TT, D);

  // softmax in place (S -> P), all rows of all batches
  softmax_kernel<<<B * T, 256, 0, stream>>>(S, T);

  // O_b = P_b V_b: 128x256 tiles, grid 16x4x4 = 256 blocks, K-capped
  gemm5<64, 2, float><<<dim3(T / 128, D / 256, B), 512, 0, stream>>>(
      S, T, TT,
      vt, M, T,
      out, D, (long)T * D, T);
}

// Round 6
// 168.335 us; speedup vs baseline: 1.8812x; 1.0251x over previous
//
#include <hip/hip_runtime.h>
#include <hip/hip_bf16.h>

typedef unsigned short u16;
typedef __attribute__((ext_vector_type(8))) short short8v;   // 8 bf16 (4 VGPR)
typedef __attribute__((ext_vector_type(4))) float float4v;   // 4 f32 acc

__device__ inline u16 f2b(float f) {
  __hip_bfloat16 h = __float2bfloat16(f);
  union { __hip_bfloat16 h; u16 s; } u;
  u.h = h;
  return u.s;
}

__device__ inline float b2f(u16 s) {
  union { u16 s[2]; float f; } u;
  u.s[0] = 0; u.s[1] = s;
  return u.f;
}

__device__ inline void gload_lds16(const u16* g, u16* l) {
  __builtin_amdgcn_global_load_lds(
      (const __attribute__((address_space(1))) void*)g,
      (__attribute__((address_space(3))) void*)l, 16, 0, 0);
}

// ---------------------------------------------------------------------------
// fp32 -> bf16 conversion (vectorized, grid-stride)
// ---------------------------------------------------------------------------
__global__ __launch_bounds__(256) void cvt_f32_bf16(const float* __restrict__ in,
                                                    u16* __restrict__ out, int n4) {
  for (int i = blockIdx.x * blockDim.x + threadIdx.x; i < n4;
       i += gridDim.x * blockDim.x) {
    float4 v = ((const float4*)in)[i];
    ushort4 o;
    o.x = f2b(v.x); o.y = f2b(v.y); o.z = f2b(v.z); o.w = f2b(v.w);
    ((ushort4*)out)[i] = o;
  }
}

// ---------------------------------------------------------------------------
// gemm6: C[m][n] = sum_k A[m][k]*B[n][k], both row-major K-contiguous.
// 128x128 tile, BK=64, 256 threads = 4 waves (2x2), 64x64 per wave.
// 2-buffer LDS (64 KB -> 2 blocks/CU; cross-block overlap covers stalls).
// Minimal sync per K-tile: {16 ds_read | stage 8 gload_lds for t+1} ->
// lgkmcnt(0)+sched_barrier -> setprio(1) 32 MFMA setprio(0) -> vmcnt(0) ->
// s_barrier.  One barrier / one lgkm / one vm wait per K-tile.
// XOR swizzle byte^=(row&7)<<4 via pre-swizzled global source (linear
// global_load_lds dest) + swizzled ds_reads (0 conflicts, verified r3-r5).
// MODE: 0 none; 1 skip tile if n0 > m0+128 (scores); 2 cap K at m0+129
//       (PV; A zero-padded by softmax to staged extent), bx heavy-first.
// ---------------------------------------------------------------------------
template <int MODE, typename CT>
__global__ __launch_bounds__(256, 2)
void gemm6(const u16* __restrict__ A, int lda, long sA,
           const u16* __restrict__ B, int ldb, long sB,
           CT* __restrict__ C, int ldc, long sC, int K) {
  constexpr int BM = 128, BN = 128;
  constexpr int A_U16 = BM * 64;                  // 8192
  constexpr int TILE_U16 = (BM + BN) * 64;        // 16384
  constexpr int TILE_BYTES = TILE_U16 * 2;        // 32768
  __shared__ __align__(16) u16 lds[2 * TILE_U16]; // 64 KiB

  const int z = blockIdx.z;
  A += (long)z * sA;
  B += (long)z * sB;

  int bx = blockIdx.x;
  if (MODE == 2) bx = gridDim.x - 1 - bx;         // heavy tiles first
  const int m0 = bx * BM;
  const int n0 = blockIdx.y * BN;
  if (MODE == 1 && n0 > m0 + BM) return;          // fully masked tile
  int Keff = K;
  if (MODE == 2) Keff = min(m0 + BM + 1, K);
  const int nk = (Keff + 63) >> 6;

  const int tid  = threadIdx.x;
  const int lane = tid & 63;
  const int wid  = tid >> 6;
  const int wr   = wid >> 1;                      // 0..1 (M)
  const int wc   = wid & 1;                       // 0..1 (N)

  // staging map: chunk c -> LDS bytes [16c,16c+16): row r=c>>3, physical
  // 16B slot (c&7) holds logical k-slot (c&7)^(r&7) -> global k-off *8.
  const u16* gsrc[8];
  int loff[8];
#pragma unroll
  for (int j = 0; j < 4; ++j) {
    int c = tid + j * 256;                        // A chunks 0..1023
    int r = c >> 3;
    int kg = ((c & 7) ^ (r & 7)) * 8;
    gsrc[j] = A + (long)(m0 + r) * lda + kg;
    loff[j] = c * 8;
  }
#pragma unroll
  for (int j = 0; j < 4; ++j) {
    int c = tid + j * 256;                        // B chunks 0..1023
    int r = c >> 3;
    int kg = ((c & 7) ^ (r & 7)) * 8;
    gsrc[4 + j] = B + (long)(n0 + r) * ldb + kg;
    loff[4 + j] = A_U16 + c * 8;
  }

#define STAGE_ALL(T_, DST_)                                                 \
  {                                                                         \
    _Pragma("unroll")                                                       \
    for (int s = 0; s < 8; ++s)                                             \
      gload_lds16(gsrc[s] + (long)(T_) * 64, (DST_) + loff[s]);             \
  }

  // ds_read swizzled byte offsets
  const int kl  = (lane >> 4) * 16;
  const int swz = (lane & 7) << 4;
  const int kx0 = kl ^ swz;
  const int kx1 = (64 + kl) ^ swz;
  const int abase = (wr * 64 + (lane & 15)) * 128;
  const int bbase = 2 * A_U16 + (wc * 64 + (lane & 15)) * 128;

  float4v acc[4][4];
#pragma unroll
  for (int i = 0; i < 4; ++i)
#pragma unroll
    for (int j = 0; j < 4; ++j)
      acc[i][j] = (float4v){0.f, 0.f, 0.f, 0.f};

  // prologue: stage tile 0 into buf 0
  STAGE_ALL(0, lds);
  asm volatile("s_waitcnt vmcnt(0)" ::: "memory");
  __builtin_amdgcn_s_barrier();

  for (int t = 0; t < nk; ++t) {
    const char* bb = (const char*)lds + (t & 1) * TILE_BYTES;
    u16* sb = lds + ((t & 1) ^ 1) * TILE_U16;

    short8v a0[4], b0[4], a1[4], b1[4];
#pragma unroll
    for (int mi = 0; mi < 4; ++mi) {
      a0[mi] = *(const short8v*)(bb + abase + mi * 2048 + kx0);
      a1[mi] = *(const short8v*)(bb + abase + mi * 2048 + kx1);
    }
#pragma unroll
    for (int ni = 0; ni < 4; ++ni) {
      b0[ni] = *(const short8v*)(bb + bbase + ni * 2048 + kx0);
      b1[ni] = *(const short8v*)(bb + bbase + ni * 2048 + kx1);
    }
    if (t + 1 < nk) STAGE_ALL(t + 1, sb);

    asm volatile("s_waitcnt lgkmcnt(0)" ::: "memory");
    __builtin_amdgcn_sched_barrier(0);
    __builtin_amdgcn_s_setprio(1);
#pragma unroll
    for (int mi = 0; mi < 4; ++mi)
#pragma unroll
      for (int ni = 0; ni < 4; ++ni)
        acc[mi][ni] = __builtin_amdgcn_mfma_f32_16x16x32_bf16(
            a0[mi], b0[ni], acc[mi][ni], 0, 0, 0);
#pragma unroll
    for (int mi = 0; mi < 4; ++mi)
#pragma unroll
      for (int ni = 0; ni < 4; ++ni)
        acc[mi][ni] = __builtin_amdgcn_mfma_f32_16x16x32_bf16(
            a1[mi], b1[ni], acc[mi][ni], 0, 0, 0);
    __builtin_amdgcn_s_setprio(0);

    asm volatile("s_waitcnt vmcnt(0)" ::: "memory");  // t+1's stage landed
    __builtin_amdgcn_s_barrier();                     // visible to all waves
  }
#undef STAGE_ALL

  // epilogue: C/D layout col = lane&15, row = (lane>>4)*4 + reg
  CT* c = C + (long)z * sC;
  const int r0base = m0 + wr * 64 + ((lane >> 4) << 2);
  const int cbase  = n0 + wc * 64 + (lane & 15);
#pragma unroll
  for (int mi = 0; mi < 4; ++mi) {
#pragma unroll
    for (int ni = 0; ni < 4; ++ni) {
      const int r0 = r0base + mi * 16;
      const int cc = cbase + ni * 16;
#pragma unroll
      for (int r = 0; r < 4; ++r) {
        float v = acc[mi][ni][r];
        if constexpr (__is_same(CT, float)) c[(long)(r0 + r) * ldc + cc] = v;
        else                                c[(long)(r0 + r) * ldc + cc] = f2b(v);
      }
    }
  }
}

// ---------------------------------------------------------------------------
// masked scaled softmax, in place on bf16 S (one row per block, B*T blocks).
// Row i sees j <= i+1; scale = 1/32. Zero-pads P up to the PV staged extent
// (tile base + 192, BM=128/BK=64).
// ---------------------------------------------------------------------------
__global__ __launch_bounds__(256)
void softmax_kernel(u16* __restrict__ SP, int T) {
  const int  i    = blockIdx.x & (T - 1);
  const long base = (long)blockIdx.x * T;
  const int  nvis = min(i + 2, T);
  const int  capJ = min(T, ((i >> 7) << 7) + 192);  // PV staging extent
  const float scale = 0.03125f;

  __shared__ float red[4];

  const int j0 = threadIdx.x * 8;
  float v[8];
  float m = -INFINITY;
  if (j0 < nvis) {
    short8v raw = *(const short8v*)&SP[base + j0];
#pragma unroll
    for (int e = 0; e < 8; ++e) {
      float f = (j0 + e < nvis) ? b2f((u16)raw[e]) * scale : -INFINITY;
      v[e] = f;
      m = fmaxf(m, f);
    }
  }
#pragma unroll
  for (int o = 32; o; o >>= 1) m = fmaxf(m, __shfl_xor(m, o));
  const int wid = threadIdx.x >> 6;
  if ((threadIdx.x & 63) == 0) red[wid] = m;
  __syncthreads();
  m = fmaxf(fmaxf(red[0], red[1]), fmaxf(red[2], red[3]));
  __syncthreads();

  float s = 0.f;
  if (j0 < nvis) {
#pragma unroll
    for (int e = 0; e < 8; ++e) {
      float p = (j0 + e < nvis) ? __expf(v[e] - m) : 0.f;
      v[e] = p;
      s += p;
    }
  }
#pragma unroll
  for (int o = 32; o; o >>= 1) s += __shfl_xor(s, o);
  if ((threadIdx.x & 63) == 0) red[wid] = s;
  __syncthreads();
  s = red[0] + red[1] + red[2] + red[3];
  const float inv = 1.0f / s;

  if (j0 < capJ) {
    short8v o8;
#pragma unroll
    for (int e = 0; e < 8; ++e)
      o8[e] = (short)f2b((j0 + e < nvis) ? v[e] * inv : 0.f);
    *(short8v*)&SP[base + j0] = o8;
  }
}

// ---------------------------------------------------------------------------
extern "C" void kernel_launch(void* const* d_in, const int* in_sizes, int n_in,
                              void* d_out, int out_size, void* d_ws, size_t ws_size,
                              hipStream_t stream) {
  const float* x  = (const float*)d_in[0];
  const float* Wq = (const float*)d_in[1];
  const float* Wk = (const float*)d_in[2];
  const float* Wv = (const float*)d_in[3];
  float* out = (float*)d_out;

  const int B = 4, T = 2048, D = 1024;
  const int M = B * T;          // 8192
  const long TT = (long)T * T;  // 4 Mi elements

  char* ws = (char*)d_ws;
  u16* qk  = (u16*)(ws);                      // 32 MiB: [8192][2048], q|k
  u16* vt  = (u16*)(ws + (32l << 20));        // 16 MiB: [1024][8192] d-major
  u16* xb  = (u16*)(ws + (48l << 20));        // 16 MiB (dead after vt GEMM)
  u16* wqk = (u16*)(ws + (64l << 20));        //  4 MiB: [2048][1024]
  u16* wv  = (u16*)(ws + (68l << 20));        //  2 MiB
  u16* S   = (u16*)(ws + (48l << 20));        // 32 MiB: 4 x [2048][2048] bf16
                                              //   (overlaps xb/wqk/wv; written
                                              //    only after they are dead)
  // peak: 80 MiB

  // fp32 -> bf16
  cvt_f32_bf16<<<2048, 256, 0, stream>>>(x,  xb,  (M * D) / 4);
  cvt_f32_bf16<<<512,  256, 0, stream>>>(Wq, wqk,               (D * D) / 4);
  cvt_f32_bf16<<<512,  256, 0, stream>>>(Wk, wqk + (long)D * D, (D * D) / 4);
  cvt_f32_bf16<<<512,  256, 0, stream>>>(Wv, wv,  (D * D) / 4);

  // qk = x @ [Wq;Wk]^T  (8192 x 2048): grid 64x16
  gemm6<0, u16><<<dim3(M / 128, 2 * D / 128, 1), 256, 0, stream>>>(
      xb, D, 0, wqk, D, 0, qk, 2 * D, 0, D);
  // vt = Wv @ x^T  (1024 x 8192, d-major): grid 8x64
  gemm6<0, u16><<<dim3(D / 128, M / 128, 1), 256, 0, stream>>>(
      wv, D, 0, xb, D, 0, vt, M, 0, D);

  // S_b = q_b k_b^T (bf16, tile-skip above diagonal): grid 16x16x4, 604 live
  gemm6<1, u16><<<dim3(T / 128, T / 128, B), 256, 0, stream>>>(
      qk, 2 * D, (long)T * 2 * D,
      qk + D, 2 * D, (long)T * 2 * D,
      S, T, TT, D);

  // softmax in place (S -> P), all rows of all batches
  softmax_kernel<<<B * T, 256, 0, stream>>>(S, T);

  // O_b = P_b V_b = P_b (vt_b)^T, K capped per tile-row: grid 16x8x4
  gemm6<2, float><<<dim3(T / 128, D / 128, B), 256, 0, stream>>>(
      S, T, TT,
      vt, M, T,
      out, D, (long)T * D, T);
}